// Round 12
// baseline (263.100 us; speedup 1.0000x reference)
//
#include <hip/hip_runtime.h>
#include <math.h>

#define N_NODES 50000
#define N_EDGES 800000
#define IN_DIM  256
#define F1      128   // HEADS*HID
#define HEADS   4
#define OUT_DIM 40
#define NEG     0.2f

// CSR bucket sort params
#define NB   391     // buckets of 128 nodes: 50000/128 -> 391
#define CAP  3072    // per-bucket capacity (mean 2048, sigma ~45 -> >20 sigma margin)
#define EB   4096    // edges per bin block

#define DCAP 96      // per-node cached edge capacity (deg ~ Poisson(16); P(>95) ~ 1e-39)

typedef __attribute__((ext_vector_type(8))) short short8;    // 8 bf16 in 4 VGPRs
typedef __attribute__((ext_vector_type(4))) float float4v;   // MFMA C/D

// ---- bf16 helpers (RNE pack, shift unpack) ----
__device__ __forceinline__ unsigned short f2bf(float f) {
  unsigned int u = __float_as_uint(f);
  u += 0x7FFF + ((u >> 16) & 1);
  return (unsigned short)(u >> 16);
}
__device__ __forceinline__ float bf2f(unsigned short h) {
  return __uint_as_float((unsigned int)h << 16);
}
__device__ __forceinline__ float bflo(unsigned int u) { return __uint_as_float(u << 16); }
__device__ __forceinline__ float bfhi(unsigned int u) { return __uint_as_float(u & 0xffff0000u); }

__device__ __forceinline__ float lrelu(float e) { return e > 0.f ? e : e * NEG; }

// ---------------- CSR build: bucketed counting sort (line-local writes) ----------------
__global__ __launch_bounds__(256) void bin_kernel(const int* __restrict__ ei,
                                                  int* __restrict__ gcnt,
                                                  int2* __restrict__ gbucket) {
  __shared__ int ls[EB];
  __shared__ int ld[EB];
  __shared__ int lcnt[NB];
  __shared__ int lcur[NB];
  __shared__ int gbaseS[NB];
  int tid = threadIdx.x;
  size_t base = (size_t)blockIdx.x * EB;
  for (int t = tid; t < NB; t += 256) { lcnt[t] = 0; lcur[t] = 0; }
  __syncthreads();
#pragma unroll
  for (int l = 0; l < EB / 256; l++) {
    int li = l * 256 + tid;
    size_t idx = base + li;
    int s = 0, d = -1;
    if (idx < N_EDGES) {
      s = ei[idx];
      d = ei[N_EDGES + idx];
      atomicAdd(&lcnt[d >> 7], 1);
    }
    ls[li] = s;
    ld[li] = d;
  }
  __syncthreads();
  for (int t = tid; t < NB; t += 256) gbaseS[t] = atomicAdd(&gcnt[t], lcnt[t]);
  __syncthreads();
#pragma unroll
  for (int l = 0; l < EB / 256; l++) {
    int li = l * 256 + tid;
    int d = ld[li];
    if (d >= 0) {
      int b = d >> 7;
      int r = gbaseS[b] + atomicAdd(&lcur[b], 1);
      if (r >= CAP) r = CAP - 1;   // overflow guard (statistically impossible)
      gbucket[(size_t)b * CAP + r] = make_int2(ls[li], d);
    }
  }
}

__global__ __launch_bounds__(512) void bucketscan_kernel(const int* __restrict__ gcnt,
                                                         int* __restrict__ bbase,
                                                         int* __restrict__ row_ptr) {
  __shared__ int lds[512];
  int tid = threadIdx.x;
  int v = (tid < NB) ? gcnt[tid] : 0;
  lds[tid] = v;
  __syncthreads();
  for (int off = 1; off < 512; off <<= 1) {
    int t = (tid >= off) ? lds[tid - off] : 0;
    __syncthreads();
    lds[tid] += t;
    __syncthreads();
  }
  if (tid < NB) bbase[tid] = lds[tid] - v;
  if (tid == 0) row_ptr[N_NODES] = N_EDGES;
}

__global__ __launch_bounds__(256) void csr_kernel(const int2* __restrict__ gbucket,
                                                  const int* __restrict__ gcnt,
                                                  const int* __restrict__ bbase,
                                                  int* __restrict__ row_ptr,
                                                  int* __restrict__ col) {
  __shared__ int2 ent[CAP];
  __shared__ int hcnt[128];
  __shared__ int sc[128];
  __shared__ int cur[128];
  int b = blockIdx.x;
  int tid = threadIdx.x;
  int cnt = gcnt[b]; if (cnt > CAP) cnt = CAP;
  int base = bbase[b];
  if (tid < 128) hcnt[tid] = 0;
  __syncthreads();
  for (int i = tid; i < cnt; i += 256) {
    int2 e = gbucket[(size_t)b * CAP + i];
    ent[i] = e;
    atomicAdd(&hcnt[e.y & 127], 1);
  }
  __syncthreads();
  if (tid < 128) sc[tid] = hcnt[tid];
  __syncthreads();
  for (int off = 1; off < 128; off <<= 1) {
    int t = 0;
    if (tid < 128 && tid >= off) t = sc[tid - off];
    __syncthreads();
    if (tid < 128) sc[tid] += t;
    __syncthreads();
  }
  if (tid < 128) {
    int excl = sc[tid] - hcnt[tid];
    cur[tid] = excl;
    int node = (b << 7) + tid;
    if (node < N_NODES) row_ptr[node] = base + excl;
  }
  __syncthreads();
  for (int i = tid; i < cnt; i += 256) {
    int2 e = ent[i];
    int r = atomicAdd(&cur[e.y & 127], 1);
    col[base + r] = e.x;
  }
}

// ---------------- W1 -> MFMA B-fragment packing (hi/lo split) ----------------
__global__ __launch_bounds__(256) void w1pack_kernel(const float* __restrict__ W1,
                                                     unsigned short* __restrict__ wHi,
                                                     unsigned short* __restrict__ wLo) {
  int tid = blockIdx.x * 256 + threadIdx.x;   // 0..4095
  int kk = tid >> 9;
  int rest = tid & 511;
  int t = rest >> 6;
  int lane = rest & 63;
  int q = lane >> 4;
  int ln = lane & 15;
  int n = t * 16 + ln;
  unsigned int hi[4], lo[4];
#pragma unroll
  for (int jj = 0; jj < 4; jj++) {
    unsigned short h0, h1, l0, l1;
    {
      float v = W1[(kk * 32 + q * 8 + jj * 2) * F1 + n];
      h0 = f2bf(v); l0 = f2bf(v - bf2f(h0));
    }
    {
      float v = W1[(kk * 32 + q * 8 + jj * 2 + 1) * F1 + n];
      h1 = f2bf(v); l1 = f2bf(v - bf2f(h1));
    }
    hi[jj] = (unsigned int)h0 | ((unsigned int)h1 << 16);
    lo[jj] = (unsigned int)l0 | ((unsigned int)l1 << 16);
  }
  size_t base = (size_t)tid * 8;
  *(uint4*)&wHi[base] = make_uint4(hi[0], hi[1], hi[2], hi[3]);
  *(uint4*)&wLo[base] = make_uint4(lo[0], lo[1], lo[2], lo[3]);
}

// ---------------- GEMM1 via bf16 MFMA (split precision) + fused alpha1 ----------------
// Grid 1564: block = 64 rows x 64 cols (half of N); wave = 16 rows x 64 cols.
// Doubled grid vs R11 -> ~6 blocks/CU (occupancy was grid-limited at 27%).
__global__ __launch_bounds__(256) void gemm1_mfma_kernel(
    const float* __restrict__ x, const unsigned short* __restrict__ wHi,
    const unsigned short* __restrict__ wLo,
    const float* __restrict__ a_src, const float* __restrict__ a_dst,
    unsigned short* __restrict__ h1b, float* __restrict__ as1, float* __restrict__ ad1) {
  int tid = threadIdx.x;
  int w = tid >> 6;
  int lane = tid & 63;
  int q = lane >> 4;
  int ln = lane & 15;
  int b = blockIdx.x;
  int rowBlk = b >> 1;
  int half = b & 1;          // column half: cols half*64 .. half*64+63
  int rowBase = rowBlk * 64 + w * 16;
  int rowA = rowBase + ln;
  int rowAc = rowA < N_NODES ? rowA : N_NODES - 1;
  float4v acc[4];
#pragma unroll
  for (int t = 0; t < 4; t++) acc[t] = (float4v){0.f, 0.f, 0.f, 0.f};
  const short8* bhp = (const short8*)wHi;
  const short8* blp = (const short8*)wLo;
  for (int kk = 0; kk < 8; kk++) {
    const float4* xp = (const float4*)(x + (size_t)rowAc * IN_DIM + kk * 32 + q * 8);
    float4 a0 = xp[0];
    float4 a1 = xp[1];
    float av[8] = {a0.x, a0.y, a0.z, a0.w, a1.x, a1.y, a1.z, a1.w};
    short8 ahi, alo;
#pragma unroll
    for (int j = 0; j < 8; j++) {
      unsigned short h = f2bf(av[j]);
      ahi[j] = (short)h;
      alo[j] = (short)f2bf(av[j] - bf2f(h));
    }
    int fbase = (kk * 8 + half * 4) * 64 + lane;
#pragma unroll
    for (int t = 0; t < 4; t++) {
      short8 bh = bhp[fbase + t * 64];
      short8 bl = blp[fbase + t * 64];
      acc[t] = __builtin_amdgcn_mfma_f32_16x16x32_bf16(ahi, bh, acc[t], 0, 0, 0);
      acc[t] = __builtin_amdgcn_mfma_f32_16x16x32_bf16(ahi, bl, acc[t], 0, 0, 0);
      acc[t] = __builtin_amdgcn_mfma_f32_16x16x32_bf16(alo, bh, acc[t], 0, 0, 0);
    }
  }
  // epilogue: C/D layout col = half*64 + t*16 + ln, row = q*4 + reg
  float asv[4], adv[4];
#pragma unroll
  for (int t = 0; t < 4; t++) {
    asv[t] = a_src[half * 64 + t * 16 + ln];
    adv[t] = a_dst[half * 64 + t * 16 + ln];
  }
#pragma unroll
  for (int reg = 0; reg < 4; reg++) {
    int r = rowBase + q * 4 + reg;
    bool valid = (r < N_NODES);
    if (valid) {
#pragma unroll
      for (int t = 0; t < 4; t++)
        h1b[(size_t)r * F1 + half * 64 + t * 16 + ln] = f2bf(acc[t][reg]);
    }
    // this col-half covers heads half*2 + {0,1}; local head lh uses tiles 2lh,2lh+1
#pragma unroll
    for (int lh = 0; lh < 2; lh++) {
      float sa = acc[2 * lh][reg] * asv[2 * lh] + acc[2 * lh + 1][reg] * asv[2 * lh + 1];
      float sd = acc[2 * lh][reg] * adv[2 * lh] + acc[2 * lh + 1][reg] * adv[2 * lh + 1];
#pragma unroll
      for (int off = 1; off < 16; off <<= 1) {
        sa += __shfl_xor(sa, off);
        sd += __shfl_xor(sd, off);
      }
      if (ln == 0 && valid) {
        as1[r * 4 + half * 2 + lh] = sa;
        ad1[r * 4 + half * 2 + lh] = sd;
      }
    }
  }
}

// ---------------- layer-1: wave-per-node gather, LDS-cached weights ----------------
__global__ __launch_bounds__(256) void gather1_kernel(
    const unsigned short* __restrict__ h1b, const float* __restrict__ as1,
    const float* __restrict__ ad1, const float* __restrict__ b1,
    const int* __restrict__ row_ptr, const int* __restrict__ col,
    float* __restrict__ x2) {
  __shared__ float4 wsh[4][DCAP];
  __shared__ int ssh[4][DCAP];
  int wv = threadIdx.x >> 6;
  int n = blockIdx.x * 4 + wv;
  if (n >= N_NODES) return;
  int lane = threadIdx.x & 63;
  int start = row_ptr[n];
  int deg = row_ptr[n + 1] - start;
  bool fast = (deg + 1) <= DCAP;
  float4 ad = *(const float4*)&ad1[n * 4];
  // phase A: per-head exp sums + LDS stash
  float s0 = 0.f, s1 = 0.f, s2 = 0.f, s3 = 0.f;
  for (int i = lane; i <= deg; i += 64) {
    int src = (i < deg) ? col[start + i] : n;
    float4 as = *(const float4*)&as1[src * 4];
    float e0 = __expf(lrelu(as.x + ad.x));
    float e1 = __expf(lrelu(as.y + ad.y));
    float e2 = __expf(lrelu(as.z + ad.z));
    float e3 = __expf(lrelu(as.w + ad.w));
    s0 += e0; s1 += e1; s2 += e2; s3 += e3;
    if (fast) {
      ssh[wv][i] = src;
      wsh[wv][i] = make_float4(e0, e1, e2, e3);
    }
  }
#pragma unroll
  for (int off = 32; off > 0; off >>= 1) {
    s0 += __shfl_xor(s0, off);
    s1 += __shfl_xor(s1, off);
    s2 += __shfl_xor(s2, off);
    s3 += __shfl_xor(s3, off);
  }
  int slot = lane >> 4;
  int lane16 = lane & 15;
  int head = lane16 >> 2;
  float rsh = (head == 0) ? s0 : (head == 1) ? s1 : (head == 2) ? s2 : s3;
  rsh = 1.f / (rsh + 1e-16f);
  float4 accA = make_float4(0.f, 0.f, 0.f, 0.f);
  float4 accB = make_float4(0.f, 0.f, 0.f, 0.f);
  if (fast) {
    const float* wp = (const float*)&wsh[wv][0];
    int i = slot;
    for (; i + 12 <= deg; i += 16) {   // unroll 4: four independent row loads in flight
      int sA = ssh[wv][i];
      int sB = ssh[wv][i + 4];
      int sC = ssh[wv][i + 8];
      int sD = ssh[wv][i + 12];
      float wA = wp[i * 4 + head] * rsh;
      float wB = wp[(i + 4) * 4 + head] * rsh;
      float wC = wp[(i + 8) * 4 + head] * rsh;
      float wD = wp[(i + 12) * 4 + head] * rsh;
      uint4 uA = *(const uint4*)(h1b + (size_t)sA * F1 + lane16 * 8);
      uint4 uB = *(const uint4*)(h1b + (size_t)sB * F1 + lane16 * 8);
      uint4 uC = *(const uint4*)(h1b + (size_t)sC * F1 + lane16 * 8);
      uint4 uD = *(const uint4*)(h1b + (size_t)sD * F1 + lane16 * 8);
      accA.x += wA * bflo(uA.x); accA.y += wA * bfhi(uA.x);
      accA.z += wA * bflo(uA.y); accA.w += wA * bfhi(uA.y);
      accB.x += wA * bflo(uA.z); accB.y += wA * bfhi(uA.z);
      accB.z += wA * bflo(uA.w); accB.w += wA * bfhi(uA.w);
      accA.x += wB * bflo(uB.x); accA.y += wB * bfhi(uB.x);
      accA.z += wB * bflo(uB.y); accA.w += wB * bfhi(uB.y);
      accB.x += wB * bflo(uB.z); accB.y += wB * bfhi(uB.z);
      accB.z += wB * bflo(uB.w); accB.w += wB * bfhi(uB.w);
      accA.x += wC * bflo(uC.x); accA.y += wC * bfhi(uC.x);
      accA.z += wC * bflo(uC.y); accA.w += wC * bfhi(uC.y);
      accB.x += wC * bflo(uC.z); accB.y += wC * bfhi(uC.z);
      accB.z += wC * bflo(uC.w); accB.w += wC * bfhi(uC.w);
      accA.x += wD * bflo(uD.x); accA.y += wD * bfhi(uD.x);
      accA.z += wD * bflo(uD.y); accA.w += wD * bfhi(uD.y);
      accB.x += wD * bflo(uD.z); accB.y += wD * bfhi(uD.z);
      accB.z += wD * bflo(uD.w); accB.w += wD * bfhi(uD.w);
    }
    for (; i <= deg; i += 4) {
      int s = ssh[wv][i];
      float w = wp[i * 4 + head] * rsh;
      uint4 u = *(const uint4*)(h1b + (size_t)s * F1 + lane16 * 8);
      accA.x += w * bflo(u.x); accA.y += w * bfhi(u.x);
      accA.z += w * bflo(u.y); accA.w += w * bfhi(u.y);
      accB.x += w * bflo(u.z); accB.y += w * bfhi(u.z);
      accB.z += w * bflo(u.w); accB.w += w * bfhi(u.w);
    }
  } else {
    float adh = (head == 0) ? ad.x : (head == 1) ? ad.y : (head == 2) ? ad.z : ad.w;
    for (int i = slot; i <= deg; i += 4) {
      int src = (i < deg) ? col[start + i] : n;
      float w = __expf(lrelu(as1[src * 4 + head] + adh)) * rsh;
      uint4 u = *(const uint4*)(h1b + (size_t)src * F1 + lane16 * 8);
      accA.x += w * bflo(u.x); accA.y += w * bfhi(u.x);
      accA.z += w * bflo(u.y); accA.w += w * bfhi(u.y);
      accB.x += w * bflo(u.z); accB.y += w * bfhi(u.z);
      accB.z += w * bflo(u.w); accB.w += w * bfhi(u.w);
    }
  }
  // cross-slot reduce: slot bits are lane bits 4,5 (clean xor butterfly)
#pragma unroll
  for (int off = 16; off <= 32; off <<= 1) {
    accA.x += __shfl_xor(accA.x, off); accA.y += __shfl_xor(accA.y, off);
    accA.z += __shfl_xor(accA.z, off); accA.w += __shfl_xor(accA.w, off);
    accB.x += __shfl_xor(accB.x, off); accB.y += __shfl_xor(accB.y, off);
    accB.z += __shfl_xor(accB.z, off); accB.w += __shfl_xor(accB.w, off);
  }
  if (slot == 0) {
    float4 bA = *(const float4*)&b1[lane16 * 8];
    float4 bB = *(const float4*)&b1[lane16 * 8 + 4];
    float4 oA, oB;
    oA.x = fmaxf(accA.x + bA.x, 0.f); oA.y = fmaxf(accA.y + bA.y, 0.f);
    oA.z = fmaxf(accA.z + bA.z, 0.f); oA.w = fmaxf(accA.w + bA.w, 0.f);
    oB.x = fmaxf(accB.x + bB.x, 0.f); oB.y = fmaxf(accB.y + bB.y, 0.f);
    oB.z = fmaxf(accB.z + bB.z, 0.f); oB.w = fmaxf(accB.w + bB.w, 0.f);
    *(float4*)&x2[(size_t)n * F1 + lane16 * 8] = oA;
    *(float4*)&x2[(size_t)n * F1 + lane16 * 8 + 4] = oB;
  }
}

// ---------------- GEMM2 tiled + alpha2 fused: h2b = x2@W2 (bf16), as2/ad2 ----------------
__global__ __launch_bounds__(256) void gemm2_kernel(
    const float* __restrict__ x2, const float* __restrict__ W2,
    const float* __restrict__ asv, const float* __restrict__ adv,
    unsigned short* __restrict__ h2b, float* __restrict__ as2, float* __restrict__ ad2) {
  __shared__ float xs[64][132];
  __shared__ float W2s[128][44];
  __shared__ float asv_s[40], adv_s[40];
  int tid = threadIdx.x;
  int bm = blockIdx.x * 64;
#pragma unroll
  for (int l = 0; l < 8; l++) {
    int idx = tid + l * 256;
    int r = idx >> 5;
    int c4 = (idx & 31) << 2;
    float4 v = make_float4(0.f, 0.f, 0.f, 0.f);
    if (bm + r < N_NODES) v = *(const float4*)&x2[(size_t)(bm + r) * F1 + c4];
    *(float4*)&xs[r][c4] = v;
  }
#pragma unroll
  for (int l = 0; l < 5; l++) {
    int idx = tid + l * 256;
    int k = idx / 10;
    int c4 = (idx - k * 10) * 4;
    *(float4*)&W2s[k][c4] = *(const float4*)&W2[k * OUT_DIM + c4];
  }
  if (tid < OUT_DIM) { asv_s[tid] = asv[tid]; adv_s[tid] = adv[tid]; }
  __syncthreads();
  int r = tid >> 2;
  int cb = (tid & 3) * 10;
  float acc[10] = {0.f};
  for (int k = 0; k < F1; k++) {
    float xv = xs[r][k];
#pragma unroll
    for (int c = 0; c < 10; c++) acc[c] += xv * W2s[k][cb + c];
  }
  int grow = bm + r;
  float sa = 0.f, sd = 0.f;
#pragma unroll
  for (int c = 0; c < 10; c++) {
    sa += acc[c] * asv_s[cb + c];
    sd += acc[c] * adv_s[cb + c];
  }
#pragma unroll
  for (int off = 1; off < 4; off <<= 1) {
    sa += __shfl_xor(sa, off);
    sd += __shfl_xor(sd, off);
  }
  if (grow < N_NODES) {
#pragma unroll
    for (int c = 0; c < 10; c += 2) {
      unsigned int p = ((unsigned int)f2bf(acc[c + 1]) << 16) | f2bf(acc[c]);
      *(unsigned int*)&h2b[(size_t)grow * OUT_DIM + cb + c] = p;
    }
    if ((tid & 3) == 0) { as2[grow] = sa; ad2[grow] = sd; }
  }
}

// ---------------- layer-2: wave-per-node gather + log_softmax, LDS-cached weights ----------------
__global__ __launch_bounds__(256) void gather2_kernel(
    const unsigned short* __restrict__ h2b, const float* __restrict__ as2,
    const float* __restrict__ ad2, const float* __restrict__ b2,
    const int* __restrict__ row_ptr, const int* __restrict__ col,
    float* __restrict__ out) {
  __shared__ float w2sh[4][DCAP];
  __shared__ int s2sh[4][DCAP];
  int wv = threadIdx.x >> 6;
  int n = blockIdx.x * 4 + wv;
  if (n >= N_NODES) return;
  int lane = threadIdx.x & 63;
  int start = row_ptr[n];
  int deg = row_ptr[n + 1] - start;
  bool fast = (deg + 1) <= DCAP;
  float adh = ad2[n];
  // phase A: exp sum + stash
  float part = 0.f;
  for (int i = lane; i <= deg; i += 64) {
    int src = (i < deg) ? col[start + i] : n;
    float e = __expf(lrelu(as2[src] + adh));
    part += e;
    if (fast) { s2sh[wv][i] = src; w2sh[wv][i] = e; }
  }
#pragma unroll
  for (int off = 32; off > 0; off >>= 1) part += __shfl_xor(part, off);
  float rs = 1.f / (part + 1e-16f);
  // phase B: 12 slots x 5 lanes (16B bf16x8, row=80B); lanes 60..63 idle
  int slot = lane / 5;
  int c = lane - slot * 5;
  float4 accA = make_float4(0.f, 0.f, 0.f, 0.f);
  float4 accB = make_float4(0.f, 0.f, 0.f, 0.f);
  if (slot < 12) {
    if (fast) {
      for (int i = slot; i <= deg; i += 12) {
        int src = s2sh[wv][i];
        float wgt = w2sh[wv][i] * rs;
        uint4 u = *(const uint4*)(h2b + (size_t)src * OUT_DIM + c * 8);
        accA.x += wgt * bflo(u.x); accA.y += wgt * bfhi(u.x);
        accA.z += wgt * bflo(u.y); accA.w += wgt * bfhi(u.y);
        accB.x += wgt * bflo(u.z); accB.y += wgt * bfhi(u.z);
        accB.z += wgt * bflo(u.w); accB.w += wgt * bfhi(u.w);
      }
    } else {
      for (int i = slot; i <= deg; i += 12) {
        int src = (i < deg) ? col[start + i] : n;
        float wgt = __expf(lrelu(as2[src] + adh)) * rs;
        uint4 u = *(const uint4*)(h2b + (size_t)src * OUT_DIM + c * 8);
        accA.x += wgt * bflo(u.x); accA.y += wgt * bfhi(u.x);
        accA.z += wgt * bflo(u.y); accA.w += wgt * bfhi(u.y);
        accB.x += wgt * bflo(u.z); accB.y += wgt * bfhi(u.z);
        accB.z += wgt * bflo(u.w); accB.w += wgt * bfhi(u.w);
      }
    }
  }
  // cross-slot reduce (12 slots); temps read before update (R7 bugfix)
  {
    float v[8] = {accA.x, accA.y, accA.z, accA.w, accB.x, accB.y, accB.z, accB.w};
#pragma unroll
    for (int k = 0; k < 8; k++) v[k] += __shfl(v[k], lane + 30);
#pragma unroll
    for (int k = 0; k < 8; k++) v[k] += __shfl(v[k], lane + 15);
    float t1[8], t2[8];
#pragma unroll
    for (int k = 0; k < 8; k++) t1[k] = __shfl(v[k], lane + 5);
#pragma unroll
    for (int k = 0; k < 8; k++) t2[k] = __shfl(v[k], lane + 10);
#pragma unroll
    for (int k = 0; k < 8; k++) v[k] += t1[k] + t2[k];
    accA.x = v[0]; accA.y = v[1]; accA.z = v[2]; accA.w = v[3];
    accB.x = v[4]; accB.y = v[5]; accB.z = v[6]; accB.w = v[7];
  }
  bool owner = (slot == 0);
  float vals[8] = {accA.x, accA.y, accA.z, accA.w, accB.x, accB.y, accB.z, accB.w};
  float lmax = -1e30f, lsum = 0.f;
  if (owner) {
#pragma unroll
    for (int k = 0; k < 8; k++) {
      vals[k] += b2[c * 8 + k];
      lmax = fmaxf(lmax, vals[k]);
    }
  }
  float gmax = lmax;
#pragma unroll
  for (int off = 32; off > 0; off >>= 1) gmax = fmaxf(gmax, __shfl_xor(gmax, off));
  if (owner) {
#pragma unroll
    for (int k = 0; k < 8; k++) lsum += __expf(vals[k] - gmax);
  }
#pragma unroll
  for (int off = 32; off > 0; off >>= 1) lsum += __shfl_xor(lsum, off);
  if (owner) {
    float lse = gmax + __logf(lsum);
    float4 oA = make_float4(vals[0] - lse, vals[1] - lse, vals[2] - lse, vals[3] - lse);
    float4 oB = make_float4(vals[4] - lse, vals[5] - lse, vals[6] - lse, vals[7] - lse);
    *(float4*)&out[(size_t)n * OUT_DIM + c * 8] = oA;
    *(float4*)&out[(size_t)n * OUT_DIM + c * 8 + 4] = oB;
  }
}

extern "C" void kernel_launch(void* const* d_in, const int* in_sizes, int n_in,
                              void* d_out, int out_size, void* d_ws, size_t ws_size,
                              hipStream_t stream) {
  const float* x      = (const float*)d_in[0];
  const int*   ei     = (const int*)d_in[1];
  const float* W1     = (const float*)d_in[2];
  const float* a_src1 = (const float*)d_in[3];
  const float* a_dst1 = (const float*)d_in[4];
  const float* b1     = (const float*)d_in[5];
  const float* W2     = (const float*)d_in[6];
  const float* a_src2 = (const float*)d_in[7];
  const float* a_dst2 = (const float*)d_in[8];
  const float* b2     = (const float*)d_in[9];
  float* out = (float*)d_out;

  char* ws = (char*)d_ws;
  size_t off = 0;
  auto alloc = [&](size_t bytes) -> void* {
    void* p = ws + off;
    off += (bytes + 255) & ~(size_t)255;
    return p;
  };
  unsigned short* h1b = (unsigned short*)alloc((size_t)N_NODES * F1 * 2);       // 12.8 MB
  unsigned short* h2b = (unsigned short*)alloc((size_t)N_NODES * OUT_DIM * 2);  // 4 MB
  unsigned short* wHi = (unsigned short*)alloc((size_t)IN_DIM * F1 * 2);        // 64 KB
  unsigned short* wLo = (unsigned short*)alloc((size_t)IN_DIM * F1 * 2);        // 64 KB
  float* as1    = (float*)alloc((size_t)N_NODES * HEADS * 4);
  float* ad1    = (float*)alloc((size_t)N_NODES * HEADS * 4);
  float* x2     = (float*)alloc((size_t)N_NODES * F1 * 4);
  float* as2    = (float*)alloc((size_t)N_NODES * 4);
  float* ad2    = (float*)alloc((size_t)N_NODES * 4);
  int* row_ptr  = (int*)alloc((size_t)(N_NODES + 1) * 4);
  int* col      = (int*)alloc((size_t)N_EDGES * 4);
  int* gcnt     = (int*)alloc((size_t)NB * 4);
  int* bbase    = (int*)alloc((size_t)NB * 4);
  int2* gbucket = (int2*)alloc((size_t)NB * CAP * 8);                           // 9.6 MB

  hipMemsetAsync(gcnt, 0, (size_t)NB * 4, stream);
  bin_kernel<<<(N_EDGES + EB - 1) / EB, 256, 0, stream>>>(ei, gcnt, gbucket);
  bucketscan_kernel<<<1, 512, 0, stream>>>(gcnt, bbase, row_ptr);
  csr_kernel<<<NB, 256, 0, stream>>>(gbucket, gcnt, bbase, row_ptr, col);

  w1pack_kernel<<<16, 256, 0, stream>>>(W1, wHi, wLo);
  gemm1_mfma_kernel<<<2 * ((N_NODES + 63) / 64), 256, 0, stream>>>(
      x, wHi, wLo, a_src1, a_dst1, h1b, as1, ad1);
  gather1_kernel<<<(N_NODES + 3) / 4, 256, 0, stream>>>(h1b, as1, ad1, b1, row_ptr, col, x2);

  gemm2_kernel<<<(N_NODES + 63) / 64, 256, 0, stream>>>(x2, W2, a_src2, a_dst2, h2b, as2, ad2);
  gather2_kernel<<<(N_NODES + 3) / 4, 256, 0, stream>>>(h2b, as2, ad2, b2, row_ptr, col, out);
}

// Round 13
// 262.884 us; speedup vs baseline: 1.0008x; 1.0008x over previous
//
#include <hip/hip_runtime.h>
#include <math.h>

#define N_NODES 50000
#define N_EDGES 800000
#define IN_DIM  256
#define F1      128   // HEADS*HID
#define HEADS   4
#define OUT_DIM 40
#define NEG     0.2f

// CSR bucket sort params
#define NB   391     // buckets of 128 nodes: 50000/128 -> 391
#define CAP  3072    // per-bucket capacity (mean 2048, sigma ~45 -> >20 sigma margin)
#define EB   4096    // edges per bin block

#define DCAP 96      // per-node cached edge capacity (deg ~ Poisson(16); P(>95) ~ 1e-39)

typedef __attribute__((ext_vector_type(8))) short short8;    // 8 bf16 in 4 VGPRs
typedef __attribute__((ext_vector_type(4))) float float4v;   // MFMA C/D

// ---- bf16 helpers (RNE pack, shift unpack) ----
__device__ __forceinline__ unsigned short f2bf(float f) {
  unsigned int u = __float_as_uint(f);
  u += 0x7FFF + ((u >> 16) & 1);
  return (unsigned short)(u >> 16);
}
__device__ __forceinline__ float bf2f(unsigned short h) {
  return __uint_as_float((unsigned int)h << 16);
}
__device__ __forceinline__ float bflo(unsigned int u) { return __uint_as_float(u << 16); }
__device__ __forceinline__ float bfhi(unsigned int u) { return __uint_as_float(u & 0xffff0000u); }

__device__ __forceinline__ float lrelu(float e) { return e > 0.f ? e : e * NEG; }

// ---------------- CSR build: bucketed counting sort (line-local writes) ----------------
__global__ __launch_bounds__(256) void bin_kernel(const int* __restrict__ ei,
                                                  int* __restrict__ gcnt,
                                                  int2* __restrict__ gbucket) {
  __shared__ int ls[EB];
  __shared__ int ld[EB];
  __shared__ int lcnt[NB];
  __shared__ int lcur[NB];
  __shared__ int gbaseS[NB];
  int tid = threadIdx.x;
  size_t base = (size_t)blockIdx.x * EB;
  for (int t = tid; t < NB; t += 256) { lcnt[t] = 0; lcur[t] = 0; }
  __syncthreads();
#pragma unroll
  for (int l = 0; l < EB / 256; l++) {
    int li = l * 256 + tid;
    size_t idx = base + li;
    int s = 0, d = -1;
    if (idx < N_EDGES) {
      s = ei[idx];
      d = ei[N_EDGES + idx];
      atomicAdd(&lcnt[d >> 7], 1);
    }
    ls[li] = s;
    ld[li] = d;
  }
  __syncthreads();
  for (int t = tid; t < NB; t += 256) gbaseS[t] = atomicAdd(&gcnt[t], lcnt[t]);
  __syncthreads();
#pragma unroll
  for (int l = 0; l < EB / 256; l++) {
    int li = l * 256 + tid;
    int d = ld[li];
    if (d >= 0) {
      int b = d >> 7;
      int r = gbaseS[b] + atomicAdd(&lcur[b], 1);
      if (r >= CAP) r = CAP - 1;   // overflow guard (statistically impossible)
      gbucket[(size_t)b * CAP + r] = make_int2(ls[li], d);
    }
  }
}

__global__ __launch_bounds__(512) void bucketscan_kernel(const int* __restrict__ gcnt,
                                                         int* __restrict__ bbase,
                                                         int* __restrict__ row_ptr) {
  __shared__ int lds[512];
  int tid = threadIdx.x;
  int v = (tid < NB) ? gcnt[tid] : 0;
  lds[tid] = v;
  __syncthreads();
  for (int off = 1; off < 512; off <<= 1) {
    int t = (tid >= off) ? lds[tid - off] : 0;
    __syncthreads();
    lds[tid] += t;
    __syncthreads();
  }
  if (tid < NB) bbase[tid] = lds[tid] - v;
  if (tid == 0) row_ptr[N_NODES] = N_EDGES;
}

__global__ __launch_bounds__(256) void csr_kernel(const int2* __restrict__ gbucket,
                                                  const int* __restrict__ gcnt,
                                                  const int* __restrict__ bbase,
                                                  int* __restrict__ row_ptr,
                                                  int* __restrict__ col) {
  __shared__ int2 ent[CAP];
  __shared__ int hcnt[128];
  __shared__ int sc[128];
  __shared__ int cur[128];
  int b = blockIdx.x;
  int tid = threadIdx.x;
  int cnt = gcnt[b]; if (cnt > CAP) cnt = CAP;
  int base = bbase[b];
  if (tid < 128) hcnt[tid] = 0;
  __syncthreads();
  for (int i = tid; i < cnt; i += 256) {
    int2 e = gbucket[(size_t)b * CAP + i];
    ent[i] = e;
    atomicAdd(&hcnt[e.y & 127], 1);
  }
  __syncthreads();
  if (tid < 128) sc[tid] = hcnt[tid];
  __syncthreads();
  for (int off = 1; off < 128; off <<= 1) {
    int t = 0;
    if (tid < 128 && tid >= off) t = sc[tid - off];
    __syncthreads();
    if (tid < 128) sc[tid] += t;
    __syncthreads();
  }
  if (tid < 128) {
    int excl = sc[tid] - hcnt[tid];
    cur[tid] = excl;
    int node = (b << 7) + tid;
    if (node < N_NODES) row_ptr[node] = base + excl;
  }
  __syncthreads();
  for (int i = tid; i < cnt; i += 256) {
    int2 e = ent[i];
    int r = atomicAdd(&cur[e.y & 127], 1);
    col[base + r] = e.x;
  }
}

// ---------------- W1 -> MFMA B-fragment packing (hi/lo split) ----------------
__global__ __launch_bounds__(256) void w1pack_kernel(const float* __restrict__ W1,
                                                     unsigned short* __restrict__ wHi,
                                                     unsigned short* __restrict__ wLo) {
  int tid = blockIdx.x * 256 + threadIdx.x;   // 0..4095
  int kk = tid >> 9;
  int rest = tid & 511;
  int t = rest >> 6;
  int lane = rest & 63;
  int q = lane >> 4;
  int ln = lane & 15;
  int n = t * 16 + ln;
  unsigned int hi[4], lo[4];
#pragma unroll
  for (int jj = 0; jj < 4; jj++) {
    unsigned short h0, h1, l0, l1;
    {
      float v = W1[(kk * 32 + q * 8 + jj * 2) * F1 + n];
      h0 = f2bf(v); l0 = f2bf(v - bf2f(h0));
    }
    {
      float v = W1[(kk * 32 + q * 8 + jj * 2 + 1) * F1 + n];
      h1 = f2bf(v); l1 = f2bf(v - bf2f(h1));
    }
    hi[jj] = (unsigned int)h0 | ((unsigned int)h1 << 16);
    lo[jj] = (unsigned int)l0 | ((unsigned int)l1 << 16);
  }
  size_t base = (size_t)tid * 8;
  *(uint4*)&wHi[base] = make_uint4(hi[0], hi[1], hi[2], hi[3]);
  *(uint4*)&wLo[base] = make_uint4(lo[0], lo[1], lo[2], lo[3]);
}

// ---------------- GEMM1 via bf16 MFMA (split precision) + fused alpha1 ----------------
// Block = 128 rows x 64 cols; wave = 32 rows (2 A-sets) x 64 cols (4 tiles).
// 2 row-sets per wave amortize B-fragment L2 reads (R12 post-mortem: kernel is
// L2-BW-bound on B re-reads; 400 MB -> 200 MB total).
__global__ __launch_bounds__(256) void gemm1_mfma_kernel(
    const float* __restrict__ x, const unsigned short* __restrict__ wHi,
    const unsigned short* __restrict__ wLo,
    const float* __restrict__ a_src, const float* __restrict__ a_dst,
    unsigned short* __restrict__ h1b, float* __restrict__ as1, float* __restrict__ ad1) {
  int tid = threadIdx.x;
  int w = tid >> 6;
  int lane = tid & 63;
  int q = lane >> 4;
  int ln = lane & 15;
  int b = blockIdx.x;
  int rowBlk = b >> 1;
  int half = b & 1;          // column half: cols half*64 .. half*64+63
  int rowBase = rowBlk * 128 + w * 32;
  int rowA0 = rowBase + ln;
  int rowA1 = rowBase + 16 + ln;
  int rowA0c = rowA0 < N_NODES ? rowA0 : N_NODES - 1;
  int rowA1c = rowA1 < N_NODES ? rowA1 : N_NODES - 1;
  float4v acc[2][4];
#pragma unroll
  for (int s = 0; s < 2; s++)
#pragma unroll
    for (int t = 0; t < 4; t++) acc[s][t] = (float4v){0.f, 0.f, 0.f, 0.f};
  const short8* bhp = (const short8*)wHi;
  const short8* blp = (const short8*)wLo;
  for (int kk = 0; kk < 8; kk++) {
    const float4* xp0 = (const float4*)(x + (size_t)rowA0c * IN_DIM + kk * 32 + q * 8);
    const float4* xp1 = (const float4*)(x + (size_t)rowA1c * IN_DIM + kk * 32 + q * 8);
    float4 a00 = xp0[0], a01 = xp0[1];
    float4 a10 = xp1[0], a11 = xp1[1];
    float av0[8] = {a00.x, a00.y, a00.z, a00.w, a01.x, a01.y, a01.z, a01.w};
    float av1[8] = {a10.x, a10.y, a10.z, a10.w, a11.x, a11.y, a11.z, a11.w};
    short8 ahi0, alo0, ahi1, alo1;
#pragma unroll
    for (int j = 0; j < 8; j++) {
      unsigned short h0 = f2bf(av0[j]);
      ahi0[j] = (short)h0;
      alo0[j] = (short)f2bf(av0[j] - bf2f(h0));
      unsigned short h1 = f2bf(av1[j]);
      ahi1[j] = (short)h1;
      alo1[j] = (short)f2bf(av1[j] - bf2f(h1));
    }
    int fbase = (kk * 8 + half * 4) * 64 + lane;
#pragma unroll
    for (int t = 0; t < 4; t++) {
      short8 bh = bhp[fbase + t * 64];
      short8 bl = blp[fbase + t * 64];
      acc[0][t] = __builtin_amdgcn_mfma_f32_16x16x32_bf16(ahi0, bh, acc[0][t], 0, 0, 0);
      acc[1][t] = __builtin_amdgcn_mfma_f32_16x16x32_bf16(ahi1, bh, acc[1][t], 0, 0, 0);
      acc[0][t] = __builtin_amdgcn_mfma_f32_16x16x32_bf16(ahi0, bl, acc[0][t], 0, 0, 0);
      acc[1][t] = __builtin_amdgcn_mfma_f32_16x16x32_bf16(ahi1, bl, acc[1][t], 0, 0, 0);
      acc[0][t] = __builtin_amdgcn_mfma_f32_16x16x32_bf16(alo0, bh, acc[0][t], 0, 0, 0);
      acc[1][t] = __builtin_amdgcn_mfma_f32_16x16x32_bf16(alo1, bh, acc[1][t], 0, 0, 0);
    }
  }
  // epilogue: C/D layout col = half*64 + t*16 + ln, row(set s) = rowBase + s*16 + q*4 + reg
  float asv[4], adv[4];
#pragma unroll
  for (int t = 0; t < 4; t++) {
    asv[t] = a_src[half * 64 + t * 16 + ln];
    adv[t] = a_dst[half * 64 + t * 16 + ln];
  }
#pragma unroll
  for (int s = 0; s < 2; s++) {
#pragma unroll
    for (int reg = 0; reg < 4; reg++) {
      int r = rowBase + s * 16 + q * 4 + reg;
      bool valid = (r < N_NODES);
      if (valid) {
#pragma unroll
        for (int t = 0; t < 4; t++)
          h1b[(size_t)r * F1 + half * 64 + t * 16 + ln] = f2bf(acc[s][t][reg]);
      }
      // this col-half covers heads half*2 + {0,1}; local head lh uses tiles 2lh,2lh+1
#pragma unroll
      for (int lh = 0; lh < 2; lh++) {
        float sa = acc[s][2 * lh][reg] * asv[2 * lh] + acc[s][2 * lh + 1][reg] * asv[2 * lh + 1];
        float sd = acc[s][2 * lh][reg] * adv[2 * lh] + acc[s][2 * lh + 1][reg] * adv[2 * lh + 1];
#pragma unroll
        for (int off = 1; off < 16; off <<= 1) {
          sa += __shfl_xor(sa, off);
          sd += __shfl_xor(sd, off);
        }
        if (ln == 0 && valid) {
          as1[r * 4 + half * 2 + lh] = sa;
          ad1[r * 4 + half * 2 + lh] = sd;
        }
      }
    }
  }
}

// ---------------- layer-1: wave-per-node gather, LDS-cached weights ----------------
__global__ __launch_bounds__(256) void gather1_kernel(
    const unsigned short* __restrict__ h1b, const float* __restrict__ as1,
    const float* __restrict__ ad1, const float* __restrict__ b1,
    const int* __restrict__ row_ptr, const int* __restrict__ col,
    float* __restrict__ x2) {
  __shared__ float4 wsh[4][DCAP];
  __shared__ int ssh[4][DCAP];
  int wv = threadIdx.x >> 6;
  int n = blockIdx.x * 4 + wv;
  if (n >= N_NODES) return;
  int lane = threadIdx.x & 63;
  int start = row_ptr[n];
  int deg = row_ptr[n + 1] - start;
  bool fast = (deg + 1) <= DCAP;
  float4 ad = *(const float4*)&ad1[n * 4];
  // phase A: per-head exp sums + LDS stash
  float s0 = 0.f, s1 = 0.f, s2 = 0.f, s3 = 0.f;
  for (int i = lane; i <= deg; i += 64) {
    int src = (i < deg) ? col[start + i] : n;
    float4 as = *(const float4*)&as1[src * 4];
    float e0 = __expf(lrelu(as.x + ad.x));
    float e1 = __expf(lrelu(as.y + ad.y));
    float e2 = __expf(lrelu(as.z + ad.z));
    float e3 = __expf(lrelu(as.w + ad.w));
    s0 += e0; s1 += e1; s2 += e2; s3 += e3;
    if (fast) {
      ssh[wv][i] = src;
      wsh[wv][i] = make_float4(e0, e1, e2, e3);
    }
  }
#pragma unroll
  for (int off = 32; off > 0; off >>= 1) {
    s0 += __shfl_xor(s0, off);
    s1 += __shfl_xor(s1, off);
    s2 += __shfl_xor(s2, off);
    s3 += __shfl_xor(s3, off);
  }
  int slot = lane >> 4;
  int lane16 = lane & 15;
  int head = lane16 >> 2;
  float rsh = (head == 0) ? s0 : (head == 1) ? s1 : (head == 2) ? s2 : s3;
  rsh = 1.f / (rsh + 1e-16f);
  float4 accA = make_float4(0.f, 0.f, 0.f, 0.f);
  float4 accB = make_float4(0.f, 0.f, 0.f, 0.f);
  if (fast) {
    const float* wp = (const float*)&wsh[wv][0];
    int i = slot;
    for (; i + 12 <= deg; i += 16) {   // unroll 4: four independent row loads in flight
      int sA = ssh[wv][i];
      int sB = ssh[wv][i + 4];
      int sC = ssh[wv][i + 8];
      int sD = ssh[wv][i + 12];
      float wA = wp[i * 4 + head] * rsh;
      float wB = wp[(i + 4) * 4 + head] * rsh;
      float wC = wp[(i + 8) * 4 + head] * rsh;
      float wD = wp[(i + 12) * 4 + head] * rsh;
      uint4 uA = *(const uint4*)(h1b + (size_t)sA * F1 + lane16 * 8);
      uint4 uB = *(const uint4*)(h1b + (size_t)sB * F1 + lane16 * 8);
      uint4 uC = *(const uint4*)(h1b + (size_t)sC * F1 + lane16 * 8);
      uint4 uD = *(const uint4*)(h1b + (size_t)sD * F1 + lane16 * 8);
      accA.x += wA * bflo(uA.x); accA.y += wA * bfhi(uA.x);
      accA.z += wA * bflo(uA.y); accA.w += wA * bfhi(uA.y);
      accB.x += wA * bflo(uA.z); accB.y += wA * bfhi(uA.z);
      accB.z += wA * bflo(uA.w); accB.w += wA * bfhi(uA.w);
      accA.x += wB * bflo(uB.x); accA.y += wB * bfhi(uB.x);
      accA.z += wB * bflo(uB.y); accA.w += wB * bfhi(uB.y);
      accB.x += wB * bflo(uB.z); accB.y += wB * bfhi(uB.z);
      accB.z += wB * bflo(uB.w); accB.w += wB * bfhi(uB.w);
      accA.x += wC * bflo(uC.x); accA.y += wC * bfhi(uC.x);
      accA.z += wC * bflo(uC.y); accA.w += wC * bfhi(uC.y);
      accB.x += wC * bflo(uC.z); accB.y += wC * bfhi(uC.z);
      accB.z += wC * bflo(uC.w); accB.w += wC * bfhi(uC.w);
      accA.x += wD * bflo(uD.x); accA.y += wD * bfhi(uD.x);
      accA.z += wD * bflo(uD.y); accA.w += wD * bfhi(uD.y);
      accB.x += wD * bflo(uD.z); accB.y += wD * bfhi(uD.z);
      accB.z += wD * bflo(uD.w); accB.w += wD * bfhi(uD.w);
    }
    for (; i <= deg; i += 4) {
      int s = ssh[wv][i];
      float w = wp[i * 4 + head] * rsh;
      uint4 u = *(const uint4*)(h1b + (size_t)s * F1 + lane16 * 8);
      accA.x += w * bflo(u.x); accA.y += w * bfhi(u.x);
      accA.z += w * bflo(u.y); accA.w += w * bfhi(u.y);
      accB.x += w * bflo(u.z); accB.y += w * bfhi(u.z);
      accB.z += w * bflo(u.w); accB.w += w * bfhi(u.w);
    }
  } else {
    float adh = (head == 0) ? ad.x : (head == 1) ? ad.y : (head == 2) ? ad.z : ad.w;
    for (int i = slot; i <= deg; i += 4) {
      int src = (i < deg) ? col[start + i] : n;
      float w = __expf(lrelu(as1[src * 4 + head] + adh)) * rsh;
      uint4 u = *(const uint4*)(h1b + (size_t)src * F1 + lane16 * 8);
      accA.x += w * bflo(u.x); accA.y += w * bfhi(u.x);
      accA.z += w * bflo(u.y); accA.w += w * bfhi(u.y);
      accB.x += w * bflo(u.z); accB.y += w * bfhi(u.z);
      accB.z += w * bflo(u.w); accB.w += w * bfhi(u.w);
    }
  }
  // cross-slot reduce: slot bits are lane bits 4,5 (clean xor butterfly)
#pragma unroll
  for (int off = 16; off <= 32; off <<= 1) {
    accA.x += __shfl_xor(accA.x, off); accA.y += __shfl_xor(accA.y, off);
    accA.z += __shfl_xor(accA.z, off); accA.w += __shfl_xor(accA.w, off);
    accB.x += __shfl_xor(accB.x, off); accB.y += __shfl_xor(accB.y, off);
    accB.z += __shfl_xor(accB.z, off); accB.w += __shfl_xor(accB.w, off);
  }
  if (slot == 0) {
    float4 bA = *(const float4*)&b1[lane16 * 8];
    float4 bB = *(const float4*)&b1[lane16 * 8 + 4];
    float4 oA, oB;
    oA.x = fmaxf(accA.x + bA.x, 0.f); oA.y = fmaxf(accA.y + bA.y, 0.f);
    oA.z = fmaxf(accA.z + bA.z, 0.f); oA.w = fmaxf(accA.w + bA.w, 0.f);
    oB.x = fmaxf(accB.x + bB.x, 0.f); oB.y = fmaxf(accB.y + bB.y, 0.f);
    oB.z = fmaxf(accB.z + bB.z, 0.f); oB.w = fmaxf(accB.w + bB.w, 0.f);
    *(float4*)&x2[(size_t)n * F1 + lane16 * 8] = oA;
    *(float4*)&x2[(size_t)n * F1 + lane16 * 8 + 4] = oB;
  }
}

// ---------------- GEMM2 tiled + alpha2 fused: h2b = x2@W2 (bf16), as2/ad2 ----------------
__global__ __launch_bounds__(256) void gemm2_kernel(
    const float* __restrict__ x2, const float* __restrict__ W2,
    const float* __restrict__ asv, const float* __restrict__ adv,
    unsigned short* __restrict__ h2b, float* __restrict__ as2, float* __restrict__ ad2) {
  __shared__ float xs[64][132];
  __shared__ float W2s[128][44];
  __shared__ float asv_s[40], adv_s[40];
  int tid = threadIdx.x;
  int bm = blockIdx.x * 64;
#pragma unroll
  for (int l = 0; l < 8; l++) {
    int idx = tid + l * 256;
    int r = idx >> 5;
    int c4 = (idx & 31) << 2;
    float4 v = make_float4(0.f, 0.f, 0.f, 0.f);
    if (bm + r < N_NODES) v = *(const float4*)&x2[(size_t)(bm + r) * F1 + c4];
    *(float4*)&xs[r][c4] = v;
  }
#pragma unroll
  for (int l = 0; l < 5; l++) {
    int idx = tid + l * 256;
    int k = idx / 10;
    int c4 = (idx - k * 10) * 4;
    *(float4*)&W2s[k][c4] = *(const float4*)&W2[k * OUT_DIM + c4];
  }
  if (tid < OUT_DIM) { asv_s[tid] = asv[tid]; adv_s[tid] = adv[tid]; }
  __syncthreads();
  int r = tid >> 2;
  int cb = (tid & 3) * 10;
  float acc[10] = {0.f};
  for (int k = 0; k < F1; k++) {
    float xv = xs[r][k];
#pragma unroll
    for (int c = 0; c < 10; c++) acc[c] += xv * W2s[k][cb + c];
  }
  int grow = bm + r;
  float sa = 0.f, sd = 0.f;
#pragma unroll
  for (int c = 0; c < 10; c++) {
    sa += acc[c] * asv_s[cb + c];
    sd += acc[c] * adv_s[cb + c];
  }
#pragma unroll
  for (int off = 1; off < 4; off <<= 1) {
    sa += __shfl_xor(sa, off);
    sd += __shfl_xor(sd, off);
  }
  if (grow < N_NODES) {
#pragma unroll
    for (int c = 0; c < 10; c += 2) {
      unsigned int p = ((unsigned int)f2bf(acc[c + 1]) << 16) | f2bf(acc[c]);
      *(unsigned int*)&h2b[(size_t)grow * OUT_DIM + cb + c] = p;
    }
    if ((tid & 3) == 0) { as2[grow] = sa; ad2[grow] = sd; }
  }
}

// ---------------- layer-2: wave-per-node gather + log_softmax, LDS-cached weights ----------------
__global__ __launch_bounds__(256) void gather2_kernel(
    const unsigned short* __restrict__ h2b, const float* __restrict__ as2,
    const float* __restrict__ ad2, const float* __restrict__ b2,
    const int* __restrict__ row_ptr, const int* __restrict__ col,
    float* __restrict__ out) {
  __shared__ float w2sh[4][DCAP];
  __shared__ int s2sh[4][DCAP];
  int wv = threadIdx.x >> 6;
  int n = blockIdx.x * 4 + wv;
  if (n >= N_NODES) return;
  int lane = threadIdx.x & 63;
  int start = row_ptr[n];
  int deg = row_ptr[n + 1] - start;
  bool fast = (deg + 1) <= DCAP;
  float adh = ad2[n];
  // phase A: exp sum + stash
  float part = 0.f;
  for (int i = lane; i <= deg; i += 64) {
    int src = (i < deg) ? col[start + i] : n;
    float e = __expf(lrelu(as2[src] + adh));
    part += e;
    if (fast) { s2sh[wv][i] = src; w2sh[wv][i] = e; }
  }
#pragma unroll
  for (int off = 32; off > 0; off >>= 1) part += __shfl_xor(part, off);
  float rs = 1.f / (part + 1e-16f);
  // phase B: 12 slots x 5 lanes (16B bf16x8, row=80B); lanes 60..63 idle
  int slot = lane / 5;
  int c = lane - slot * 5;
  float4 accA = make_float4(0.f, 0.f, 0.f, 0.f);
  float4 accB = make_float4(0.f, 0.f, 0.f, 0.f);
  if (slot < 12) {
    if (fast) {
      for (int i = slot; i <= deg; i += 12) {
        int src = s2sh[wv][i];
        float wgt = w2sh[wv][i] * rs;
        uint4 u = *(const uint4*)(h2b + (size_t)src * OUT_DIM + c * 8);
        accA.x += wgt * bflo(u.x); accA.y += wgt * bfhi(u.x);
        accA.z += wgt * bflo(u.y); accA.w += wgt * bfhi(u.y);
        accB.x += wgt * bflo(u.z); accB.y += wgt * bfhi(u.z);
        accB.z += wgt * bflo(u.w); accB.w += wgt * bfhi(u.w);
      }
    } else {
      for (int i = slot; i <= deg; i += 12) {
        int src = (i < deg) ? col[start + i] : n;
        float wgt = __expf(lrelu(as2[src] + adh)) * rs;
        uint4 u = *(const uint4*)(h2b + (size_t)src * OUT_DIM + c * 8);
        accA.x += wgt * bflo(u.x); accA.y += wgt * bfhi(u.x);
        accA.z += wgt * bflo(u.y); accA.w += wgt * bfhi(u.y);
        accB.x += wgt * bflo(u.z); accB.y += wgt * bfhi(u.z);
        accB.z += wgt * bflo(u.w); accB.w += wgt * bfhi(u.w);
      }
    }
  }
  // cross-slot reduce (12 slots); temps read before update (R7 bugfix)
  {
    float v[8] = {accA.x, accA.y, accA.z, accA.w, accB.x, accB.y, accB.z, accB.w};
#pragma unroll
    for (int k = 0; k < 8; k++) v[k] += __shfl(v[k], lane + 30);
#pragma unroll
    for (int k = 0; k < 8; k++) v[k] += __shfl(v[k], lane + 15);
    float t1[8], t2[8];
#pragma unroll
    for (int k = 0; k < 8; k++) t1[k] = __shfl(v[k], lane + 5);
#pragma unroll
    for (int k = 0; k < 8; k++) t2[k] = __shfl(v[k], lane + 10);
#pragma unroll
    for (int k = 0; k < 8; k++) v[k] += t1[k] + t2[k];
    accA.x = v[0]; accA.y = v[1]; accA.z = v[2]; accA.w = v[3];
    accB.x = v[4]; accB.y = v[5]; accB.z = v[6]; accB.w = v[7];
  }
  bool owner = (slot == 0);
  float vals[8] = {accA.x, accA.y, accA.z, accA.w, accB.x, accB.y, accB.z, accB.w};
  float lmax = -1e30f, lsum = 0.f;
  if (owner) {
#pragma unroll
    for (int k = 0; k < 8; k++) {
      vals[k] += b2[c * 8 + k];
      lmax = fmaxf(lmax, vals[k]);
    }
  }
  float gmax = lmax;
#pragma unroll
  for (int off = 32; off > 0; off >>= 1) gmax = fmaxf(gmax, __shfl_xor(gmax, off));
  if (owner) {
#pragma unroll
    for (int k = 0; k < 8; k++) lsum += __expf(vals[k] - gmax);
  }
#pragma unroll
  for (int off = 32; off > 0; off >>= 1) lsum += __shfl_xor(lsum, off);
  if (owner) {
    float lse = gmax + __logf(lsum);
    float4 oA = make_float4(vals[0] - lse, vals[1] - lse, vals[2] - lse, vals[3] - lse);
    float4 oB = make_float4(vals[4] - lse, vals[5] - lse, vals[6] - lse, vals[7] - lse);
    *(float4*)&out[(size_t)n * OUT_DIM + c * 8] = oA;
    *(float4*)&out[(size_t)n * OUT_DIM + c * 8 + 4] = oB;
  }
}

extern "C" void kernel_launch(void* const* d_in, const int* in_sizes, int n_in,
                              void* d_out, int out_size, void* d_ws, size_t ws_size,
                              hipStream_t stream) {
  const float* x      = (const float*)d_in[0];
  const int*   ei     = (const int*)d_in[1];
  const float* W1     = (const float*)d_in[2];
  const float* a_src1 = (const float*)d_in[3];
  const float* a_dst1 = (const float*)d_in[4];
  const float* b1     = (const float*)d_in[5];
  const float* W2     = (const float*)d_in[6];
  const float* a_src2 = (const float*)d_in[7];
  const float* a_dst2 = (const float*)d_in[8];
  const float* b2     = (const float*)d_in[9];
  float* out = (float*)d_out;

  char* ws = (char*)d_ws;
  size_t off = 0;
  auto alloc = [&](size_t bytes) -> void* {
    void* p = ws + off;
    off += (bytes + 255) & ~(size_t)255;
    return p;
  };
  unsigned short* h1b = (unsigned short*)alloc((size_t)N_NODES * F1 * 2);       // 12.8 MB
  unsigned short* h2b = (unsigned short*)alloc((size_t)N_NODES * OUT_DIM * 2);  // 4 MB
  unsigned short* wHi = (unsigned short*)alloc((size_t)IN_DIM * F1 * 2);        // 64 KB
  unsigned short* wLo = (unsigned short*)alloc((size_t)IN_DIM * F1 * 2);        // 64 KB
  float* as1    = (float*)alloc((size_t)N_NODES * HEADS * 4);
  float* ad1    = (float*)alloc((size_t)N_NODES * HEADS * 4);
  float* x2     = (float*)alloc((size_t)N_NODES * F1 * 4);
  float* as2    = (float*)alloc((size_t)N_NODES * 4);
  float* ad2    = (float*)alloc((size_t)N_NODES * 4);
  int* row_ptr  = (int*)alloc((size_t)(N_NODES + 1) * 4);
  int* col      = (int*)alloc((size_t)N_EDGES * 4);
  int* gcnt     = (int*)alloc((size_t)NB * 4);
  int* bbase    = (int*)alloc((size_t)NB * 4);
  int2* gbucket = (int2*)alloc((size_t)NB * CAP * 8);                           // 9.6 MB

  hipMemsetAsync(gcnt, 0, (size_t)NB * 4, stream);
  bin_kernel<<<(N_EDGES + EB - 1) / EB, 256, 0, stream>>>(ei, gcnt, gbucket);
  bucketscan_kernel<<<1, 512, 0, stream>>>(gcnt, bbase, row_ptr);
  csr_kernel<<<NB, 256, 0, stream>>>(gbucket, gcnt, bbase, row_ptr, col);

  w1pack_kernel<<<16, 256, 0, stream>>>(W1, wHi, wLo);
  gemm1_mfma_kernel<<<2 * ((N_NODES + 127) / 128), 256, 0, stream>>>(
      x, wHi, wLo, a_src1, a_dst1, h1b, as1, ad1);
  gather1_kernel<<<(N_NODES + 3) / 4, 256, 0, stream>>>(h1b, as1, ad1, b1, row_ptr, col, x2);

  gemm2_kernel<<<(N_NODES + 63) / 64, 256, 0, stream>>>(x2, W2, a_src2, a_dst2, h2b, as2, ad2);
  gather2_kernel<<<(N_NODES + 3) / 4, 256, 0, stream>>>(h2b, as2, ad2, b2, row_ptr, col, out);
}